// Round 8
// baseline (115.036 us; speedup 1.0000x reference)
//
#include <hip/hip_runtime.h>

#define BATCH 131072

typedef float v2f __attribute__((ext_vector_type(2)));

// ws layout (floats):
//  [0..53]     A: 6 matrices 3x3 (decoder collapsed: recon_k = (l^T A_k l)/(l^T l))
//  [64..99]    enc RX coeffs: gate g=bb*6+w -> ws[64+2g]=cos(tx/2), ws[65+2g]=sin(tx/2)
//  [128..511]  enc diag per block bb: ws[128+128*bb+2r]=Re D_r, +1=Im D_r

__device__ __forceinline__ float fast_tanh(float v) {
    float e = __expf(2.0f * v);
    return 1.0f - 2.0f / (e + 1.0f);
}

__device__ __forceinline__ v2f swap2(v2f v) { return __builtin_shufflevector(v, v, 1, 0); }

// sWI physical base for logical pack p (pad 4 floats every 2 packs: epilogue
// sub-stride becomes 144 ≡ 16 mod 32 -> 2-way bank aliasing = free)
__device__ __forceinline__ int wbase(int p) { return p * 16 + (p >> 1) * 4; }

// ---------------------------------------------------------------------------
// prep (unchanged)
// ---------------------------------------------------------------------------
__global__ __launch_bounds__(256) void prep_kernel(const float* __restrict__ enc_w,
                                                   const float* __restrict__ dec_w,
                                                   float* __restrict__ ws) {
    __shared__ float gt[18][8];
    __shared__ float Sr[64][8];
    __shared__ float Si[64][8];
    const int t = threadIdx.x;

    if (t < 18) {
        float tx = dec_w[t * 3 + 0];
        float tz = dec_w[t * 3 + 1];
        float c = cosf(0.5f * tx), s = sinf(0.5f * tx);
        float ch = cosf(0.5f * tz), sh = sinf(0.5f * tz);
        gt[t][0] = c * ch;  gt[t][1] = -c * sh;
        gt[t][2] = -s * sh; gt[t][3] = -s * ch;
        gt[t][4] = s * sh;  gt[t][5] = -s * ch;
        gt[t][6] = c * ch;  gt[t][7] = c * sh;
    }

    const int cl = t & 7;
    const int pr = t >> 3;
    float* fSr = &Sr[0][0];
    float* fSi = &Si[0][0];
    for (int f = t; f < 512; f += 256) {
        int r = f >> 3, c = f & 7;
        fSr[f] = (r == c && c < 3) ? 1.0f : 0.0f;
        fSi[f] = 0.0f;
    }

    for (int bb = 0; bb < 3; ++bb) {
        for (int w = 0; w < 6; ++w) {
            __syncthreads();
            int g = bb * 6 + w;
            int p = 5 - w;
            float u00r = gt[g][0], u00i = gt[g][1], u01r = gt[g][2], u01i = gt[g][3];
            float u10r = gt[g][4], u10i = gt[g][5], u11r = gt[g][6], u11i = gt[g][7];
            int r0 = ((pr >> p) << (p + 1)) | (pr & ((1 << p) - 1));
            int r1 = r0 | (1 << p);
            float ar = Sr[r0][cl], ai = Si[r0][cl];
            float br = Sr[r1][cl], bi = Si[r1][cl];
            Sr[r0][cl] = u00r * ar - u00i * ai + u01r * br - u01i * bi;
            Si[r0][cl] = u00r * ai + u00i * ar + u01r * bi + u01i * br;
            Sr[r1][cl] = u10r * ar - u10i * ai + u11r * br - u11i * bi;
            Si[r1][cl] = u10r * ai + u10i * ar + u11r * bi + u11i * br;
        }
        __syncthreads();
        for (int f = t; f < 512; f += 256) {
            int r = f >> 3;
            if (__popc(r & (r >> 1)) & 1) {
                fSr[f] = -fSr[f];
                fSi[f] = -fSi[f];
            }
        }
    }
    __syncthreads();

    if (t < 54) {
        int k = t / 9, d = (t % 9) / 3, e = t % 3;
        float acc = 0.0f;
        for (int r = 0; r < 64; ++r) {
            float term = Sr[r][d] * Sr[r][e] + Si[r][d] * Si[r][e];
            acc += ((r >> (5 - k)) & 1) ? -term : term;
        }
        ws[t] = acc;
    }

    if (t < 18) {
        float tx = enc_w[t * 3 + 0];
        ws[64 + 2 * t] = cosf(0.5f * tx);
        ws[65 + 2 * t] = sinf(0.5f * tx);
    }

    if (t >= 64 && t < 256) {
        int idx = t - 64;
        int bb = idx >> 6, r = idx & 63;
        float phi = 0.0f;
        for (int k = 0; k < 6; ++k) {
            float tz = enc_w[(bb * 6 + k) * 3 + 1];
            phi += ((r >> (5 - k)) & 1) ? 0.5f * tz : -0.5f * tz;
        }
        float sgn = (__popc(r & (r >> 1)) & 1) ? -1.0f : 1.0f;
        ws[128 + bb * 128 + 2 * r] = sgn * cosf(phi);
        ws[129 + bb * 128 + 2 * r] = sgn * sinf(phi);
    }
}

// ---------------------------------------------------------------------------
// Solo-state butterflies: 32 v2f packs/thread; pack p = amps (2p, 2p+1).
// Wire w<5 acts on p bit (4-w); wire 5 is the in-pack stage.
// ---------------------------------------------------------------------------
template <int MASK>
__device__ __forceinline__ void rx32(v2f* zr, v2f* zi, float c, float s) {
#pragma unroll
    for (int p = 0; p < 32; ++p) {
        if (p & MASK) continue;
        int p1 = p | MASK;
        v2f ar = zr[p], ai = zi[p], br = zr[p1], bi = zi[p1];
        zr[p]  = c * ar + s * bi;
        zi[p]  = c * ai - s * br;
        zr[p1] = c * br + s * ai;
        zi[p1] = c * bi - s * ar;
    }
}

template <int MASK>  // first wire of block 0: state still real (zi = 0)
__device__ __forceinline__ void rx32_real(v2f* zr, v2f* zi, float c, float s) {
#pragma unroll
    for (int p = 0; p < 32; ++p) {
        if (p & MASK) continue;
        int p1 = p | MASK;
        v2f ar = zr[p], br = zr[p1];
        zr[p]  = c * ar;  zi[p]  = -s * br;
        zr[p1] = c * br;  zi[p1] = -s * ar;
    }
}

__device__ __forceinline__ void rx32_inpack(v2f* zr, v2f* zi, float c, float s) {
#pragma unroll
    for (int p = 0; p < 32; ++p) {
        v2f orr = zr[p], oi = zi[p];
        zr[p] = c * orr + s * swap2(oi);
        zi[p] = c * oi - s * swap2(orr);
    }
}

template <int BB>
__device__ __forceinline__ void enc_block(v2f* zr, v2f* zi, const float* rxc,
                                          const float* sD) {
    if (BB == 0) rx32_real<16>(zr, zi, rxc[12 * BB + 0], rxc[12 * BB + 1]);
    else         rx32<16>(zr, zi, rxc[12 * BB + 0], rxc[12 * BB + 1]);
    rx32<8>(zr, zi, rxc[12 * BB + 2], rxc[12 * BB + 3]);
    rx32<4>(zr, zi, rxc[12 * BB + 4], rxc[12 * BB + 5]);
    rx32<2>(zr, zi, rxc[12 * BB + 6], rxc[12 * BB + 7]);
    rx32<1>(zr, zi, rxc[12 * BB + 8], rxc[12 * BB + 9]);
    rx32_inpack(zr, zi, rxc[12 * BB + 10], rxc[12 * BB + 11]);
    if (BB < 2) {
#pragma unroll
        for (int p = 0; p < 32; ++p) {
            float4 d = *(const float4*)&sD[BB * 128 + 4 * p];  // wave-uniform broadcast
            v2f dr = {d.x, d.z}, di = {d.y, d.w};
            v2f orr = zr[p], oi = zi[p];
            zr[p] = dr * orr - di * oi;
            zi[p] = dr * oi + di * orr;
        }
    }
}

// ---------------------------------------------------------------------------
// main: ONE thread per batch element; full state in registers; all shared
// operands wave-uniform (no DPP, no cross-lane). NO second launch_bounds arg
// (R6's (256,2) cap -> 128-VGPR limit -> spills was the regression cause).
// Epilogue: LDS transpose + 4-lane/element float4 writes (R4-proven, ideal
// WRITE_SIZE).
// ---------------------------------------------------------------------------
__global__ __launch_bounds__(256) void qae_main(const float* __restrict__ x,
                                                const float* __restrict__ Wp,
                                                const float* __restrict__ bp,
                                                const float* __restrict__ ws,
                                                float* __restrict__ out) {
    __shared__ float sWI[572];      // pack p at wbase(p): 12 W + 2 bias + pad
    __shared__ float sD[256];       // blocks 0,1 diagonals (block 2's is dead)
    __shared__ float sRec[6 * 256]; // d-major: conflict-free write & read

    const int t = threadIdx.x;

    for (int f = t; f < 512; f += 256) {
        int p = f >> 4, e = f & 15;
        float val = 0.0f;
        if (e < 12)      val = Wp[(2 * p + (e & 1)) * 6 + (e >> 1)];
        else if (e < 14) val = bp[2 * p + (e - 12)];
        sWI[wbase(p) + e] = val;
    }
    if (t < 256) sD[t] = ws[128 + t];

    // all 36 gate coeffs: uniform -> SGPRs
    float rxc[36];
#pragma unroll
    for (int i = 0; i < 36; ++i) rxc[i] = ws[64 + i];
    __syncthreads();

    const size_t b = (size_t)blockIdx.x * 256 + t;
    const float* xp = x + b * 6;
    float2 x01 = *(const float2*)(xp);
    float2 x23 = *(const float2*)(xp + 2);
    float2 x45 = *(const float2*)(xp + 4);
    float xv[6] = {x01.x, x01.y, x23.x, x23.y, x45.x, x45.y};

    // h = tanh(xW^T + b); pack p = rows (2p, 2p+1); W reads wave-uniform
    v2f zr[32], zi[32];
    v2f S2 = {0.0f, 0.0f};
#pragma unroll
    for (int p = 0; p < 32; ++p) {
        const float* wb = &sWI[wbase(p)];
        float4 c0 = *(const float4*)wb;
        float4 c1 = *(const float4*)(wb + 4);
        float4 c2 = *(const float4*)(wb + 8);
        float4 c3 = *(const float4*)(wb + 12);
        v2f a = {c3.x, c3.y};
        a += xv[0] * (v2f){c0.x, c0.y};
        a += xv[1] * (v2f){c0.z, c0.w};
        a += xv[2] * (v2f){c1.x, c1.y};
        a += xv[3] * (v2f){c1.z, c1.w};
        a += xv[4] * (v2f){c2.x, c2.y};
        a += xv[5] * (v2f){c2.z, c2.w};
        v2f th = {fast_tanh(a.x), fast_tanh(a.y)};
        zr[p] = th;
        zi[p] = (v2f){0.0f, 0.0f};
        S2 += th * th;
    }
    float invS = __builtin_amdgcn_rcpf(S2.x + S2.y);

    // encoder circuit, fully register-local
    enc_block<0>(zr, zi, rxc, sD);
    enc_block<1>(zr, zi, rxc, sD);
    enc_block<2>(zr, zi, rxc, sD);

    // latent: signs from amp bits 5,4,3 = p bits 4,3,2; thread-local
    v2f L0 = {0, 0}, L1 = {0, 0}, L2 = {0, 0};
#pragma unroll
    for (int p = 0; p < 32; ++p) {
        v2f pr = zr[p] * zr[p] + zi[p] * zi[p];
        L0 += (p & 16) ? -pr : pr;
        L1 += (p & 8) ? -pr : pr;
        L2 += (p & 4) ? -pr : pr;
    }
    float l0 = (L0.x + L0.y) * invS;
    float l1 = (L1.x + L1.y) * invS;
    float l2 = (L2.x + L2.y) * invS;

    // decoder collapsed: recon_k = (l^T A_k l)/(l^T l)  (A uniform -> s_load)
    float r2 = l0 * l0 + l1 * l1 + l2 * l2;
    float invr2 = __builtin_amdgcn_rcpf(r2);
    float lv[3] = {l0, l1, l2};
    float rec[6];
#pragma unroll
    for (int k = 0; k < 6; ++k) {
        float acc = 0.0f;
#pragma unroll
        for (int d = 0; d < 3; ++d)
#pragma unroll
            for (int e2 = 0; e2 < 3; ++e2) acc += ws[k * 9 + d * 3 + e2] * lv[d] * lv[e2];
        rec[k] = acc * invr2;
    }

    // latent out: wave writes 768 contiguous bytes
    {
        const size_t lb = (size_t)BATCH * 64 + b * 3;
        out[lb + 0] = l0;
        out[lb + 1] = l1;
        out[lb + 2] = l2;
    }

    // stage rec (d-major: lanes consecutive -> conflict-free)
#pragma unroll
    for (int d = 0; d < 6; ++d) sRec[d * 256 + t] = rec[d];
    __syncthreads();

    // epilogue: 4 lanes/element, element el = 64q + (t>>2); rows 16*sub..+15
    const int bl = t >> 2, sub = t & 3;
    const size_t obase = (size_t)blockIdx.x * 256 * 64;
#pragma unroll
    for (int q = 0; q < 4; ++q) {
        int el = 64 * q + bl;
        float rc[6];
#pragma unroll
        for (int d = 0; d < 6; ++d) rc[d] = sRec[d * 256 + el];  // quad broadcast
        const size_t ob = obase + (size_t)el * 64 + sub * 16;
#pragma unroll
        for (int gg = 0; gg < 2; ++gg) {
            float vals[8];
#pragma unroll
            for (int pp = 0; pp < 4; ++pp) {
                int p = 8 * sub + 4 * gg + pp;   // sub-stride 144 floats: 2-way (free)
                const float* wb = &sWI[wbase(p)];
                float4 c0 = *(const float4*)wb;
                float4 c1 = *(const float4*)(wb + 4);
                float4 c2 = *(const float4*)(wb + 8);
                float2 b2 = *(const float2*)(wb + 12);
                v2f a = {b2.x, b2.y};
                a += rc[0] * (v2f){c0.x, c0.y};
                a += rc[1] * (v2f){c0.z, c0.w};
                a += rc[2] * (v2f){c1.x, c1.y};
                a += rc[3] * (v2f){c1.z, c1.w};
                a += rc[4] * (v2f){c2.x, c2.y};
                a += rc[5] * (v2f){c2.z, c2.w};
                vals[2 * pp]     = fast_tanh(a.x);
                vals[2 * pp + 1] = fast_tanh(a.y);
            }
            float4 o0 = {vals[0], vals[1], vals[2], vals[3]};
            float4 o1 = {vals[4], vals[5], vals[6], vals[7]};
            *(float4*)&out[ob + 8 * gg]     = o0;
            *(float4*)&out[ob + 8 * gg + 4] = o1;
        }
    }
}

extern "C" void kernel_launch(void* const* d_in, const int* in_sizes, int n_in,
                              void* d_out, int out_size, void* d_ws, size_t ws_size,
                              hipStream_t stream) {
    const float* x   = (const float*)d_in[0];
    const float* Wp  = (const float*)d_in[1];
    const float* bpv = (const float*)d_in[2];
    const float* enc = (const float*)d_in[3];
    const float* dec = (const float*)d_in[4];
    float* out = (float*)d_out;
    float* ws  = (float*)d_ws;

    prep_kernel<<<1, 256, 0, stream>>>(enc, dec, ws);
    qae_main<<<BATCH / 256, 256, 0, stream>>>(x, Wp, bpv, ws, out);
}